// Round 5
// baseline (1470.260 us; speedup 1.0000x reference)
//
#include <hip/hip_runtime.h>

// 5-layer GRU, H=20, B=256, T=4096, fp32. PyTorch GRU math.
// One block per batch element. Waves 0-4 = layers (R7-exact math: packed-f2
// hh matvec, single-sigmoid + bpermute z/ghn gathers, pre-scaled weights:
// -log2e on r/z rows, -2log2e on n rows). Pairwise flag sync on depth-4
// rings (no per-chunk __syncthreads).
//
// R11: PROJ OFFLOAD TO HELPER WAVES. Evidence R6->R10: pace is set by the
// one SIMD carrying two layer waves (5 waves / 4 SIMDs); adding issue work
// (R10 matvecB) scaled time up ~30%, removing DS latency didn't help ->
// issue-bound, not latency-bound. So: producers no longer compute the next
// layer's x-projection (~21 issue slots/step); they publish h(t) (one
// ds_write from 20 lanes) into an h-ring. Two helper waves (w5: layers 0,1;
// w6: layers 2,3) broadcast-read h rows (5x ds_read_b128, wave-uniform,
// conflict-free) and produce the x-ring rows. Helper math replicates the
// old proj() fma pairing exactly; h bits from LDS == producer's broadcast
// bits -> bit-identical output. R10's permlane zswap reverted (regression
// + 4.45M LDS-crossbar conflicts).

#define HH 20
#define GG 60
#define NL 5
#define BB 256
#define TT 4096
#define KK 16
#define NC (TT / KK)
#define RD 4            // ring depth (chunks of drift allowed)
#define NW 7            // 5 layer waves + 2 helper waves

typedef float f2 __attribute__((ext_vector_type(2)));
typedef float f4 __attribute__((ext_vector_type(4)));

struct Params {
  const float* x;
  const float* wih[NL];
  const float* whh[NL];
  const float* bih[NL];
  const float* bhh[NL];
  const float* wout;
  const float* bout;
  float* out;
};

__device__ __forceinline__ float bcast(float v, int j) {        // j: imm
  return __int_as_float(__builtin_amdgcn_readlane(__float_as_int(v), j));
}
__device__ __forceinline__ float bcast_dyn(float v, int j) {    // j: sgpr
  return __int_as_float(__builtin_amdgcn_readlane(__float_as_int(v), j));
}
__device__ __forceinline__ float shfl_idx(float v, int byteidx) {
  return __int_as_float(__builtin_amdgcn_ds_bpermute(byteidx, __float_as_int(v)));
}
// input pre-scaled by -log2e: sigmoid(x) = rcp(1 + exp2(x_scaled))
__device__ __forceinline__ float fsig_s(float xs) {
  return __builtin_amdgcn_rcpf(1.0f + __builtin_amdgcn_exp2f(xs));
}
// input pre-scaled by -2log2e: tanh(y) = 2*rcp(1 + exp2(y_scaled)) - 1
__device__ __forceinline__ float ftanh_s(float ys) {
  return fmaf(2.0f, __builtin_amdgcn_rcpf(1.0f + __builtin_amdgcn_exp2f(ys)), -1.0f);
}
__device__ __forceinline__ int ldv(const int* p) {
  return *(const volatile int*)p;
}

__global__ __launch_bounds__(NW * 64, 1) void gru5_kernel(Params p) {
  // x-ring: helper for layer l writes xring[l][c%RD]; layer l+1 reads.
  // KK+1 rows so the consumer's t+1 prefetch is unguarded (row KK = junk).
  __shared__ float xring[NL - 1][RD][KK + 1][64];
  // h-ring: layer l (0..3) writes h(t) rows; its helper reads them.
  __shared__ float hring[NL - 1][RD][KK][HH];
  __shared__ float yp[NL];
  __shared__ int prog_h[NL - 1];   // h-ring chunks published by layer l
  __shared__ int cons_h[NL - 1];   // h-ring chunks consumed by helper(l)
  __shared__ int prog_x[NL - 1];   // x-ring chunks published by helper(l)
  __shared__ int cons_x[NL - 1];   // x-ring chunks consumed by layer l+1

  const int tid = threadIdx.x;
  const int w = tid >> 6;          // wave index
  const int lane = tid & 63;
  const int b = blockIdx.x;

  if (tid < NL - 1) {
    prog_h[tid] = 0; cons_h[tid] = 0; prog_x[tid] = 0; cons_x[tid] = 0;
  }

  const float S1 = -1.44269504088896f;   // -log2(e)      (r/z rows)
  const float S2 = -2.88539008177793f;   // -2*log2(e)    (n rows)

  if (w < NL) {
    // ================= layer wave (R7-exact recurrence) =================
    const int l = w;
    const int g = lane < GG ? lane : GG - 1;            // gate owned by lane
    const int gn = lane < HH ? lane + 2 * HH : GG - 1;  // n-gate row for unit lane
    const float scg = (g < 2 * HH) ? S1 : S2;

    f2 whh2[HH / 2];
    {
      const float* W = p.whh[l];
      #pragma unroll
      for (int j = 0; j < HH / 2; ++j) {
        whh2[j].x = W[g * HH + 2 * j]     * scg;
        whh2[j].y = W[g * HH + 2 * j + 1] * scg;
      }
    }
    const float binit = (g >= 2 * HH) ? p.bhh[l][g] * S2 : 0.0f;

    float w0own = 0.f, b0own = 0.f, w0n = 0.f, b0n = 0.f;
    if (l == 0) {
      w0own = p.wih[0][g] * scg;
      b0own = (p.bih[0][g] + (g < 2 * HH ? p.bhh[0][g] : 0.0f)) * scg;
      w0n = p.wih[0][gn] * S2;
      b0n = p.bih[0][gn] * S2;          // b_ih only (b_hh_n stays in binit)
    }

    const int idx20 = ((lane + 20) & 63) << 2;   // bpermute byte indices
    const int idx40 = ((lane + 40) & 63) << 2;

    float hreg = 0.0f;               // lanes 0..19 carry h[unit]
    f2 hs2[HH / 2];                  // wave-uniform broadcast of h
    #pragma unroll
    for (int j = 0; j < HH / 2; ++j) { hs2[j].x = 0.0f; hs2[j].y = 0.0f; }

    const float* xrow = p.x + (size_t)b * TT;
    float* hout = p.out + (size_t)b * TT * HH;

    auto matvec = [&]() -> float {   // scaled (W_hh h)[g] (+b_hh_n on n rows)
      f2 a0; a0.x = binit; a0.y = 0.0f;
      f2 a1; a1.x = 0.0f;  a1.y = 0.0f;
      #pragma unroll
      for (int j = 0; j < HH / 2; j += 2) {
        a0 = __builtin_elementwise_fma(whh2[j],     hs2[j],     a0);
        a1 = __builtin_elementwise_fma(whh2[j + 1], hs2[j + 1], a1);
      }
      f2 s = a0 + a1;
      return s.x + s.y;
    };
    auto refresh_hs = [&]() {
      #pragma unroll
      for (int j = 0; j < HH / 2; ++j) {
        hs2[j].x = bcast(hreg, 2 * j);
        hs2[j].y = bcast(hreg, 2 * j + 1);
      }
    };
    auto gru_step = [&](float xr, float xn) {
      const float gh = matvec();
      const float sv = xr + gh;                 // scaled preact (r/z rows)
      const float sg = fsig_s(sv);              // r in unit lanes, z in z-rows
      const float zf = shfl_idx(sg, idx20);     // cooked z for unit lane
      const float ghn = shfl_idx(gh, idx40);    // n-gate h-proj (+b_hh_n)
      const float n = ftanh_s(fmaf(sg, ghn, xn));
      hreg = fmaf(zf, hreg - n, n);             // (1-z)*n + z*h
    };

    __syncthreads();                 // flags initialized

    float xstage = 0.0f;
    if (l == 0 && lane < KK) xstage = xrow[lane];

    for (int c = 0; c < NC; ++c) {
      // wait for input chunk; backpressure on h-ring slot reuse
      if (l > 0) {
        while (ldv(&prog_x[l - 1]) < c + 1) __builtin_amdgcn_s_sleep(1);
      }
      if (l < NL - 1) {
        while (ldv(&cons_h[l]) < c + 1 - RD) __builtin_amdgcn_s_sleep(1);
      }

      float* hdst = (l < NL - 1) ? &hring[l][c & (RD - 1)][0][0] : nullptr;

      if (l == 0) {
        float xnl = 0.0f;
        if (lane < KK && c + 1 < NC) xnl = xrow[(c + 1) * KK + lane];
        for (int t = 0; t < KK; ++t) {
          const float xv = bcast_dyn(xstage, t);
          gru_step(fmaf(w0own, xv, b0own), fmaf(w0n, xv, b0n));
          if (lane < HH) hdst[t * HH + lane] = hreg;    // publish h(t)
          refresh_hs();
        }
        xstage = xnl;
      } else if (l < NL - 1) {
        const float* src = &xring[l - 1][c & (RD - 1)][0][0];
        float xr_c = src[g];
        float xn_c = src[gn];
        for (int t = 0; t < KK; ++t) {
          const float* nsrc = src + (t + 1) * 64;   // row KK exists (junk)
          const float xr_n = nsrc[g];
          const float xn_n = nsrc[gn];
          gru_step(xr_c, xn_c);
          if (lane < HH) hdst[t * HH + lane] = hreg;
          refresh_hs();
          xr_c = xr_n; xn_c = xn_n;
        }
      } else {
        const float* src = &xring[NL - 2][c & (RD - 1)][0][0];
        float* hp = hout + (size_t)c * KK * HH;
        float xr_c = src[g];
        float xn_c = src[gn];
        for (int t = 0; t < KK; ++t) {
          const float* nsrc = src + (t + 1) * 64;
          const float xr_n = nsrc[g];
          const float xn_n = nsrc[gn];
          gru_step(xr_c, xn_c);
          if (lane < HH) hp[t * HH + lane] = hreg;   // fire-and-forget
          refresh_hs();
          xr_c = xr_n; xn_c = xn_n;
        }
      }

      if (l < NL - 1) {
        __threadfence_block();               // drain h-ring writes
        if (lane == 0) *(volatile int*)&prog_h[l] = c + 1;
      }
      if (l > 0) {
        if (lane == 0) *(volatile int*)&cons_x[l - 1] = c + 1;
      }
    }

    // ---- epilogue: h_n + y_hat partial ----
    if (lane < HH)
      p.out[(size_t)BB * TT * HH + (size_t)b * NL * HH + l * HH + lane] = hreg;
    float pp = (lane < HH) ? hreg * p.wout[l * HH + lane] : 0.0f;
    #pragma unroll
    for (int off = 32; off > 0; off >>= 1) pp += __shfl_down(pp, off);
    if (lane == 0) yp[l] = pp;

  } else {
    // ================= helper wave: x-projection producer =================
    const int lA = (w == NL) ? 0 : 2;   // serves layers lA and lA+1
    const int lB = lA + 1;
    const int g = lane < GG ? lane : GG - 1;
    const float scg = (g < 2 * HH) ? S1 : S2;

    f2 wnA[HH / 2], wnB[HH / 2];
    float bnA, bnB;
    {
      const float* WA = p.wih[lA + 1];
      const float* WB = p.wih[lB + 1];
      #pragma unroll
      for (int j = 0; j < HH / 2; ++j) {
        wnA[j].x = WA[g * HH + 2 * j]     * scg;
        wnA[j].y = WA[g * HH + 2 * j + 1] * scg;
        wnB[j].x = WB[g * HH + 2 * j]     * scg;
        wnB[j].y = WB[g * HH + 2 * j + 1] * scg;
      }
      bnA = (p.bih[lA + 1][g] + (g < 2 * HH ? p.bhh[lA + 1][g] : 0.0f)) * scg;
      bnB = (p.bih[lB + 1][g] + (g < 2 * HH ? p.bhh[lB + 1][g] : 0.0f)) * scg;
    }

    __syncthreads();                 // flags initialized

    for (int c = 0; c < NC; ++c) {
      #pragma unroll
      for (int which = 0; which < 2; ++which) {
        const int li = which ? lB : lA;
        const f2* wn = which ? wnB : wnA;
        const float bn = which ? bnB : bnA;

        while (ldv(&prog_h[li]) < c + 1) __builtin_amdgcn_s_sleep(1);
        while (ldv(&cons_x[li]) < c + 1 - RD) __builtin_amdgcn_s_sleep(1);

        const float* hb = &hring[li][c & (RD - 1)][0][0];
        float* dst = &xring[li][c & (RD - 1)][0][0];
        #pragma unroll
        for (int t = 0; t < KK; ++t) {
          const f4* hv = (const f4*)(hb + t * HH);   // wave-uniform: bcast reads
          const f4 q0 = hv[0], q1 = hv[1], q2 = hv[2], q3 = hv[3], q4 = hv[4];
          f2 h0, h1, h2, h3, h4, h5, h6, h7, h8, h9;
          h0.x = q0.x; h0.y = q0.y;  h1.x = q0.z; h1.y = q0.w;
          h2.x = q1.x; h2.y = q1.y;  h3.x = q1.z; h3.y = q1.w;
          h4.x = q2.x; h4.y = q2.y;  h5.x = q2.z; h5.y = q2.w;
          h6.x = q3.x; h6.y = q3.y;  h7.x = q3.z; h7.y = q3.w;
          h8.x = q4.x; h8.y = q4.y;  h9.x = q4.z; h9.y = q4.w;
          // same pairing as the old proj(): c0 over even j, c1 over odd j
          f2 c0; c0.x = bn;   c0.y = 0.0f;
          f2 c1; c1.x = 0.0f; c1.y = 0.0f;
          c0 = __builtin_elementwise_fma(wn[0], h0, c0);
          c1 = __builtin_elementwise_fma(wn[1], h1, c1);
          c0 = __builtin_elementwise_fma(wn[2], h2, c0);
          c1 = __builtin_elementwise_fma(wn[3], h3, c1);
          c0 = __builtin_elementwise_fma(wn[4], h4, c0);
          c1 = __builtin_elementwise_fma(wn[5], h5, c1);
          c0 = __builtin_elementwise_fma(wn[6], h6, c0);
          c1 = __builtin_elementwise_fma(wn[7], h7, c1);
          c0 = __builtin_elementwise_fma(wn[8], h8, c0);
          c1 = __builtin_elementwise_fma(wn[9], h9, c1);
          f2 s = c0 + c1;
          dst[t * 64 + lane] = s.x + s.y;
        }
        __threadfence_block();             // drain x-ring writes
        if (lane == 0) *(volatile int*)&prog_x[li] = c + 1;
        if (lane == 0) *(volatile int*)&cons_h[li] = c + 1;
      }
    }
  }

  __syncthreads();
  if (tid == 0) {
    float y = p.bout[0];
    #pragma unroll
    for (int ll = 0; ll < NL; ++ll) y += yp[ll];
    p.out[(size_t)BB * TT * HH + (size_t)BB * NL * HH + b] = y;
  }
}

extern "C" void kernel_launch(void* const* d_in, const int* in_sizes, int n_in,
                              void* d_out, int out_size, void* d_ws, size_t ws_size,
                              hipStream_t stream) {
  Params p;
  p.x = (const float*)d_in[0];
  for (int l = 0; l < NL; ++l) {
    p.wih[l] = (const float*)d_in[1 + 4 * l];
    p.whh[l] = (const float*)d_in[2 + 4 * l];
    p.bih[l] = (const float*)d_in[3 + 4 * l];
    p.bhh[l] = (const float*)d_in[4 + 4 * l];
  }
  p.wout = (const float*)d_in[1 + 4 * NL];
  p.bout = (const float*)d_in[2 + 4 * NL];
  p.out = (float*)d_out;

  gru5_kernel<<<BB, NW * 64, 0, stream>>>(p);
}

// Round 6
// 1294.947 us; speedup vs baseline: 1.1354x; 1.1354x over previous
//
#include <hip/hip_runtime.h>

// 5-layer GRU, H=20, B=256, T=4096, fp32. PyTorch GRU math.
// One block per batch element; 5 waves = one per layer. Lane g owns gate g
// (20-FMA hh matvec); producer wave computes the next layer's input
// projection from its h-broadcast SGPRs. Pre-scaled weights (-log2e on r/z
// rows, -2log2e on n rows) so sigmoid/tanh need no leading multiply.
// Pairwise flag sync on depth-4 ring (no per-chunk __syncthreads).
//
// R12: FORCED v_pk_fma_f32. Evidence R6-R11: dur tracks total VALU
// instruction count at ~55% fixed utilization (R11 redistributed work with
// zero net change -> zero gain); slot accounting says the f2
// __builtin_elementwise_fma chains scalarized (R7's gain was the trans cut
// only). So: matvec and proj now use inline-asm v_pk_fma_f32 / v_pk_add_f32.
// The h-broadcast operand uses an "s" constraint (readlane results already
// live in SGPRs; VOP3P permits 1 scalar source) so no SGPR->VGPR movs are
// added; weights stay in VGPR pairs; accumulator is tied ("+v").
// Same op order as R7's scalar sequence -> bit-identical numerics.

#define HH 20
#define GG 60
#define NL 5
#define BB 256
#define TT 4096
#define KK 16
#define NC (TT / KK)
#define RD 4            // ring depth (chunks of drift allowed)

typedef float f2 __attribute__((ext_vector_type(2)));

struct Params {
  const float* x;
  const float* wih[NL];
  const float* whh[NL];
  const float* bih[NL];
  const float* bhh[NL];
  const float* wout;
  const float* bout;
  float* out;
};

__device__ __forceinline__ float bcast(float v, int j) {        // j: imm
  return __int_as_float(__builtin_amdgcn_readlane(__float_as_int(v), j));
}
__device__ __forceinline__ float bcast_dyn(float v, int j) {    // j: sgpr
  return __int_as_float(__builtin_amdgcn_readlane(__float_as_int(v), j));
}
__device__ __forceinline__ float shfl_idx(float v, int byteidx) {
  return __int_as_float(__builtin_amdgcn_ds_bpermute(byteidx, __float_as_int(v)));
}
// input pre-scaled by -log2e: sigmoid(x) = rcp(1 + exp2(x_scaled))
__device__ __forceinline__ float fsig_s(float xs) {
  return __builtin_amdgcn_rcpf(1.0f + __builtin_amdgcn_exp2f(xs));
}
// input pre-scaled by -2log2e: tanh(y) = 2*rcp(1 + exp2(y_scaled)) - 1
__device__ __forceinline__ float ftanh_s(float ys) {
  return fmaf(2.0f, __builtin_amdgcn_rcpf(1.0f + __builtin_amdgcn_exp2f(ys)), -1.0f);
}
__device__ __forceinline__ int ldv(const int* p) {
  return *(const volatile int*)p;
}
// acc += w * h, packed fp32. w: VGPR pair (per-lane weights), h: SGPR pair
// (wave-uniform broadcast — VOP3P allows one scalar source), acc tied.
__device__ __forceinline__ void pk_fma_s(f2& acc, f2 w, f2 h) {
  asm("v_pk_fma_f32 %0, %1, %2, %0" : "+v"(acc) : "v"(w), "s"(h));
}
__device__ __forceinline__ f2 pk_add(f2 a, f2 b) {
  f2 d;
  asm("v_pk_add_f32 %0, %1, %2" : "=v"(d) : "v"(a), "v"(b));
  return d;
}

__global__ __launch_bounds__(NL * 64, 1) void gru5_kernel(Params p) {
  // ring: producer layer l (0..3) writes xring[l][c%RD]; consumer l+1 reads.
  // KK+1 rows so the consumer's t+1 prefetch is unguarded (row KK = junk).
  __shared__ float xring[NL - 1][RD][KK + 1][64];
  __shared__ float yp[NL];
  __shared__ int prog[NL - 1];   // chunks produced by layer l
  __shared__ int cons[NL - 1];   // chunks consumed by layer l+1

  const int tid = threadIdx.x;
  const int l = tid >> 6;          // wave index == layer
  const int lane = tid & 63;
  const int b = blockIdx.x;
  const int g = lane < GG ? lane : GG - 1;            // gate owned by lane
  const int gn = lane < HH ? lane + 2 * HH : GG - 1;  // n-gate column for unit lane

  if (tid < NL - 1) { prog[tid] = 0; cons[tid] = 0; }

  const float S1 = -1.44269504088896f;   // -log2(e)      (r/z rows)
  const float S2 = -2.88539008177793f;   // -2*log2(e)    (n rows)
  const float scg = (g < 2 * HH) ? S1 : S2;

  // ---- weights into registers (packed pairs), pre-scaled ----
  f2 whh2[HH / 2];
  {
    const float* W = p.whh[l];
    #pragma unroll
    for (int j = 0; j < HH / 2; ++j) {
      whh2[j].x = W[g * HH + 2 * j]     * scg;
      whh2[j].y = W[g * HH + 2 * j + 1] * scg;
    }
  }
  const float binit = (g >= 2 * HH) ? p.bhh[l][g] * S2 : 0.0f;

  f2 wnx2[HH / 2];
  float bnx = 0.0f;
  if (l < NL - 1) {
    const float* W = p.wih[l + 1];
    #pragma unroll
    for (int j = 0; j < HH / 2; ++j) {
      wnx2[j].x = W[g * HH + 2 * j]     * scg;
      wnx2[j].y = W[g * HH + 2 * j + 1] * scg;
    }
    bnx = (p.bih[l + 1][g] + (g < 2 * HH ? p.bhh[l + 1][g] : 0.0f)) * scg;
  } else {
    #pragma unroll
    for (int j = 0; j < HH / 2; ++j) { wnx2[j].x = 0.0f; wnx2[j].y = 0.0f; }
  }
  float w0own = 0.f, b0own = 0.f, w0n = 0.f, b0n = 0.f;
  if (l == 0) {
    w0own = p.wih[0][g] * scg;
    b0own = (p.bih[0][g] + (g < 2 * HH ? p.bhh[0][g] : 0.0f)) * scg;
    w0n = p.wih[0][gn] * S2;
    b0n = p.bih[0][gn] * S2;          // b_ih only (b_hh_n stays in binit)
  }

  const int idx20 = ((lane + 20) & 63) << 2;   // bpermute byte indices
  const int idx40 = ((lane + 40) & 63) << 2;

  float hreg = 0.0f;               // lanes 0..19 carry h[unit]
  f2 hs2[HH / 2];                  // wave-uniform broadcast of h (SGPR pairs)
  #pragma unroll
  for (int j = 0; j < HH / 2; ++j) { hs2[j].x = 0.0f; hs2[j].y = 0.0f; }

  const float* xrow = p.x + (size_t)b * TT;
  float* hout = p.out + (size_t)b * TT * HH;

  // hh matvec: scaled (W_hh h)[g] (+ b_hh_n on n rows). Packed; same
  // accumulation order as R7's scalar sequence -> bit-identical.
  auto matvec = [&]() -> float {
    f2 a0; a0.x = binit; a0.y = 0.0f;
    f2 a1; a1.x = 0.0f;  a1.y = 0.0f;
    #pragma unroll
    for (int j = 0; j < HH / 2; j += 2) {
      pk_fma_s(a0, whh2[j],     hs2[j]);
      pk_fma_s(a1, whh2[j + 1], hs2[j + 1]);
    }
    f2 s = pk_add(a0, a1);
    return s.x + s.y;
  };
  auto refresh_hs = [&]() {
    #pragma unroll
    for (int j = 0; j < HH / 2; ++j) {
      hs2[j].x = bcast(hreg, 2 * j);
      hs2[j].y = bcast(hreg, 2 * j + 1);
    }
  };
  auto proj = [&]() -> float {     // next layer's xg value for this lane
    f2 c0; c0.x = bnx;  c0.y = 0.0f;
    f2 c1; c1.x = 0.0f; c1.y = 0.0f;
    #pragma unroll
    for (int j = 0; j < HH / 2; j += 2) {
      pk_fma_s(c0, wnx2[j],     hs2[j]);
      pk_fma_s(c1, wnx2[j + 1], hs2[j + 1]);
    }
    f2 s = pk_add(c0, c1);
    return s.x + s.y;
  };

  __syncthreads();                 // flags initialized

  // prime layer-0 x stage for chunk 0 (lanes 0..KK-1 hold the chunk's x)
  float xstage = 0.0f;
  if (l == 0 && lane < KK) xstage = xrow[lane];

  for (int c = 0; c < NC; ++c) {
    // --- sync: wait for input chunk; backpressure on ring slot reuse ---
    if (l > 0) {
      while (ldv(&prog[l - 1]) < c + 1) __builtin_amdgcn_s_sleep(1);
    }
    if (l < NL - 1) {
      while (ldv(&cons[l]) < c + 1 - RD) __builtin_amdgcn_s_sleep(1);
    }

    if (l == 0) {
      float* dst = &xring[0][c & (RD - 1)][0][0];
      // prefetch next chunk's x (a whole chunk of latency to hide)
      float xnl = 0.0f;
      if (lane < KK && c + 1 < NC) xnl = xrow[(c + 1) * KK + lane];
      for (int t = 0; t < KK; ++t) {
        const float xv = bcast_dyn(xstage, t);
        const float xr = fmaf(w0own, xv, b0own);
        const float xn = fmaf(w0n, xv, b0n);
        const float gh = matvec();
        const float sv = xr + gh;                 // scaled full preact (r/z rows)
        const float sg = __builtin_amdgcn_rcpf(1.0f + __builtin_amdgcn_exp2f(sv));
        const float zf = shfl_idx(sg, idx20);     // cooked z for unit lane
        const float ghn = shfl_idx(gh, idx40);    // n-gate h-proj (+b_hh_n)
        if (t > 0) dst[(t - 1) * 64 + lane] = proj();   // shadow: row t-1 (h(t-1))
        const float n = ftanh_s(fmaf(sg, ghn, xn));
        hreg = fmaf(zf, hreg - n, n);             // (1-z)*n + z*h
        refresh_hs();
      }
      dst[(KK - 1) * 64 + lane] = proj();         // flush last row before flag
      xstage = xnl;
    } else if (l < NL - 1) {
      const float* src = &xring[l - 1][c & (RD - 1)][0][0];
      float* dst = &xring[l][c & (RD - 1)][0][0];
      float xr_c = src[g];
      float xn_c = src[gn];
      for (int t = 0; t < KK; ++t) {
        const float* nsrc = src + (t + 1) * 64;   // row KK exists (junk, dead)
        const float xr_n = nsrc[g];
        const float xn_n = nsrc[gn];
        const float gh = matvec();
        const float sv = xr_c + gh;
        const float sg = __builtin_amdgcn_rcpf(1.0f + __builtin_amdgcn_exp2f(sv));
        const float zf = shfl_idx(sg, idx20);
        const float ghn = shfl_idx(gh, idx40);
        if (t > 0) dst[(t - 1) * 64 + lane] = proj();
        const float n = ftanh_s(fmaf(sg, ghn, xn_c));
        hreg = fmaf(zf, hreg - n, n);
        refresh_hs();
        xr_c = xr_n; xn_c = xn_n;
      }
      dst[(KK - 1) * 64 + lane] = proj();
    } else {
      const float* src = &xring[NL - 2][c & (RD - 1)][0][0];
      float* hp = hout + (size_t)c * KK * HH;
      float xr_c = src[g];
      float xn_c = src[gn];
      for (int t = 0; t < KK; ++t) {
        const float* nsrc = src + (t + 1) * 64;
        const float xr_n = nsrc[g];
        const float xn_n = nsrc[gn];
        const float gh = matvec();
        const float sv = xr_c + gh;
        const float sg = __builtin_amdgcn_rcpf(1.0f + __builtin_amdgcn_exp2f(sv));
        const float zf = shfl_idx(sg, idx20);
        const float ghn = shfl_idx(gh, idx40);
        if (t > 0 && lane < HH) hp[(t - 1) * HH + lane] = hreg;  // h(t-1), fire-and-forget
        const float n = ftanh_s(fmaf(sg, ghn, xn_c));
        hreg = fmaf(zf, hreg - n, n);
        refresh_hs();                       // keeps hs fresh for next iter
        xr_c = xr_n; xn_c = xn_n;
      }
      if (lane < HH) hp[(KK - 1) * HH + lane] = hreg;
    }

    // --- publish: producer flags chunk done; consumer frees ring slot ---
    if (l < NL - 1) {
      __threadfence_block();               // drain LDS writes before flag
      if (lane == 0) *(volatile int*)&prog[l] = c + 1;
    }
    if (l > 0) {
      if (lane == 0) *(volatile int*)&cons[l - 1] = c + 1;
    }
  }

  // ---- epilogue: h_n + y_hat partial (per wave, then one final barrier) ----
  if (lane < HH)
    p.out[(size_t)BB * TT * HH + (size_t)b * NL * HH + l * HH + lane] = hreg;
  float pp = (lane < HH) ? hreg * p.wout[l * HH + lane] : 0.0f;
  #pragma unroll
  for (int off = 32; off > 0; off >>= 1) pp += __shfl_down(pp, off);
  if (lane == 0) yp[l] = pp;

  __syncthreads();
  if (tid == 0) {
    float y = p.bout[0];
    #pragma unroll
    for (int ll = 0; ll < NL; ++ll) y += yp[ll];
    p.out[(size_t)BB * TT * HH + (size_t)BB * NL * HH + b] = y;
  }
}

extern "C" void kernel_launch(void* const* d_in, const int* in_sizes, int n_in,
                              void* d_out, int out_size, void* d_ws, size_t ws_size,
                              hipStream_t stream) {
  Params p;
  p.x = (const float*)d_in[0];
  for (int l = 0; l < NL; ++l) {
    p.wih[l] = (const float*)d_in[1 + 4 * l];
    p.whh[l] = (const float*)d_in[2 + 4 * l];
    p.bih[l] = (const float*)d_in[3 + 4 * l];
    p.bhh[l] = (const float*)d_in[4 + 4 * l];
  }
  p.wout = (const float*)d_in[1 + 4 * NL];
  p.bout = (const float*)d_in[2 + 4 * NL];
  p.out = (float*)d_out;

  gru5_kernel<<<BB, NL * 64, 0, stream>>>(p);
}

// Round 7
// 1218.386 us; speedup vs baseline: 1.2067x; 1.0628x over previous
//
#include <hip/hip_runtime.h>

// 5-layer GRU, H=20, B=256, T=4096, fp32. PyTorch GRU math.
// One block per batch element; 5 waves = one per layer. Lane g owns gate g
// (20-FMA hh matvec). Pre-scaled weights (-log2e on r/z rows, -2log2e on n
// rows) so sigmoid/tanh need no leading multiply. Pairwise flag sync on
// depth-4 rings (no per-chunk __syncthreads).
//
// R13: PACE-SIMD REBALANCE. Waves map to SIMDs as w%4 -> L0+L4 share SIMD0,
// which sets the pace (VALUBusy ~55% = 1 saturated SIMD + 3 at ~40%).
// Evidence R6-R12: dur tracks total VALU-busy cycles; redistribution onto
// the SAME SIMD (R11) and asm micro-management (R12) both failed. This
// round moves L0's x-projection duty to L1 (which lives alone on SIMD1
// with slack): L0 publishes raw h(t) rows to an h-ring (20-lane ds_write,
// sheds ~24 slots/step); L1 reads the row wave-uniform (5x ds_read_b128,
// broadcast, conflict-free) and computes its own xr in-lane with the EXACT
// proj pairing (bit-identical); the n-row xn lives in lane gn and reaches
// the unit lane via one extra idx40 bpermute. L1 still writes xring[1] for
// L2; layers 2-4 are byte-identical to R7 (best verified: 1070 us).

#define HH 20
#define GG 60
#define NL 5
#define BB 256
#define TT 4096
#define KK 16
#define NC (TT / KK)
#define RD 4            // ring depth (chunks of drift allowed)

typedef float f2 __attribute__((ext_vector_type(2)));
typedef float f4 __attribute__((ext_vector_type(4)));

struct Params {
  const float* x;
  const float* wih[NL];
  const float* whh[NL];
  const float* bih[NL];
  const float* bhh[NL];
  const float* wout;
  const float* bout;
  float* out;
};

__device__ __forceinline__ float bcast(float v, int j) {        // j: imm
  return __int_as_float(__builtin_amdgcn_readlane(__float_as_int(v), j));
}
__device__ __forceinline__ float bcast_dyn(float v, int j) {    // j: sgpr
  return __int_as_float(__builtin_amdgcn_readlane(__float_as_int(v), j));
}
__device__ __forceinline__ float shfl_idx(float v, int byteidx) {
  return __int_as_float(__builtin_amdgcn_ds_bpermute(byteidx, __float_as_int(v)));
}
// input pre-scaled by -2log2e: tanh(y) = 2*rcp(1 + exp2(y_scaled)) - 1
__device__ __forceinline__ float ftanh_s(float ys) {
  return fmaf(2.0f, __builtin_amdgcn_rcpf(1.0f + __builtin_amdgcn_exp2f(ys)), -1.0f);
}
__device__ __forceinline__ int ldv(const int* p) {
  return *(const volatile int*)p;
}

__global__ __launch_bounds__(NL * 64, 1) void gru5_kernel(Params p) {
  // x-ring: producer layer l (1..3) writes xring[l][c%RD]; consumer l+1
  // reads. Slot 0 unused in R13 (kept to avoid index churn). KK+1 rows so
  // the consumer's t+1 prefetch is unguarded (row KK = junk).
  __shared__ float xring[NL - 1][RD][KK + 1][64];
  // h-ring: L0 publishes h(t) rows; L1 broadcast-reads them.
  __shared__ __align__(16) float hring[RD][KK][HH];
  __shared__ float yp[NL];
  __shared__ int prog[NL - 1];   // chunks produced by layer l
  __shared__ int cons[NL - 1];   // chunks consumed by layer l+1

  const int tid = threadIdx.x;
  const int l = tid >> 6;          // wave index == layer
  const int lane = tid & 63;
  const int b = blockIdx.x;
  const int g = lane < GG ? lane : GG - 1;            // gate owned by lane
  const int gn = lane < HH ? lane + 2 * HH : GG - 1;  // n-gate row for unit lane

  if (tid < NL - 1) { prog[tid] = 0; cons[tid] = 0; }

  const float S1 = -1.44269504088896f;   // -log2(e)      (r/z rows)
  const float S2 = -2.88539008177793f;   // -2*log2(e)    (n rows)
  const float scg = (g < 2 * HH) ? S1 : S2;

  // ---- weights into registers (packed pairs), pre-scaled ----
  f2 whh2[HH / 2];
  {
    const float* W = p.whh[l];
    #pragma unroll
    for (int j = 0; j < HH / 2; ++j) {
      whh2[j].x = W[g * HH + 2 * j]     * scg;
      whh2[j].y = W[g * HH + 2 * j + 1] * scg;
    }
  }
  const float binit = (g >= 2 * HH) ? p.bhh[l][g] * S2 : 0.0f;

  // next-layer proj weights: only waves 1..3 produce xring now
  f2 wnx2[HH / 2];
  float bnx = 0.0f;
  if (l >= 1 && l < NL - 1) {
    const float* W = p.wih[l + 1];
    #pragma unroll
    for (int j = 0; j < HH / 2; ++j) {
      wnx2[j].x = W[g * HH + 2 * j]     * scg;
      wnx2[j].y = W[g * HH + 2 * j + 1] * scg;
    }
    bnx = (p.bih[l + 1][g] + (g < 2 * HH ? p.bhh[l + 1][g] : 0.0f)) * scg;
  } else {
    #pragma unroll
    for (int j = 0; j < HH / 2; ++j) { wnx2[j].x = 0.0f; wnx2[j].y = 0.0f; }
  }
  // L1's OWN input-projection weights (W_ih[1]), same scaling convention
  f2 wself2[HH / 2];
  float bself = 0.0f;
  if (l == 1) {
    const float* W = p.wih[1];
    #pragma unroll
    for (int j = 0; j < HH / 2; ++j) {
      wself2[j].x = W[g * HH + 2 * j]     * scg;
      wself2[j].y = W[g * HH + 2 * j + 1] * scg;
    }
    bself = (p.bih[1][g] + (g < 2 * HH ? p.bhh[1][g] : 0.0f)) * scg;
  } else {
    #pragma unroll
    for (int j = 0; j < HH / 2; ++j) { wself2[j].x = 0.0f; wself2[j].y = 0.0f; }
  }
  float w0own = 0.f, b0own = 0.f, w0n = 0.f, b0n = 0.f;
  if (l == 0) {
    w0own = p.wih[0][g] * scg;
    b0own = (p.bih[0][g] + (g < 2 * HH ? p.bhh[0][g] : 0.0f)) * scg;
    w0n = p.wih[0][gn] * S2;
    b0n = p.bih[0][gn] * S2;          // b_ih only (b_hh_n stays in binit)
  }

  const int idx20 = ((lane + 20) & 63) << 2;   // bpermute byte indices
  const int idx40 = ((lane + 40) & 63) << 2;

  float hreg = 0.0f;               // lanes 0..19 carry h[unit]
  f2 hs2[HH / 2];                  // wave-uniform broadcast of h (SGPR pairs)
  #pragma unroll
  for (int j = 0; j < HH / 2; ++j) { hs2[j].x = 0.0f; hs2[j].y = 0.0f; }

  const float* xrow = p.x + (size_t)b * TT;
  float* hout = p.out + (size_t)b * TT * HH;

  // hh matvec: scaled (W_hh h)[g] (+ b_hh_n on n rows)
  auto matvec = [&]() -> float {
    f2 a0; a0.x = binit; a0.y = 0.0f;
    f2 a1; a1.x = 0.0f;  a1.y = 0.0f;
    #pragma unroll
    for (int j = 0; j < HH / 2; j += 2) {
      a0 = __builtin_elementwise_fma(whh2[j],     hs2[j],     a0);
      a1 = __builtin_elementwise_fma(whh2[j + 1], hs2[j + 1], a1);
    }
    f2 s = a0 + a1;
    return s.x + s.y;
  };
  auto refresh_hs = [&]() {
    #pragma unroll
    for (int j = 0; j < HH / 2; ++j) {
      hs2[j].x = bcast(hreg, 2 * j);
      hs2[j].y = bcast(hreg, 2 * j + 1);
    }
  };
  auto proj = [&]() -> float {     // next layer's xg value for this lane
    f2 c0; c0.x = bnx;  c0.y = 0.0f;
    f2 c1; c1.x = 0.0f; c1.y = 0.0f;
    #pragma unroll
    for (int j = 0; j < HH / 2; j += 2) {
      c0 = __builtin_elementwise_fma(wnx2[j],     hs2[j],     c0);
      c1 = __builtin_elementwise_fma(wnx2[j + 1], hs2[j + 1], c1);
    }
    f2 s = c0 + c1;
    return s.x + s.y;
  };

  __syncthreads();                 // flags initialized

  // prime layer-0 x stage for chunk 0 (lanes 0..KK-1 hold the chunk's x)
  float xstage = 0.0f;
  if (l == 0 && lane < KK) xstage = xrow[lane];

  for (int c = 0; c < NC; ++c) {
    // --- sync: wait for input chunk; backpressure on ring slot reuse ---
    if (l > 0) {
      while (ldv(&prog[l - 1]) < c + 1) __builtin_amdgcn_s_sleep(1);
    }
    if (l < NL - 1) {
      while (ldv(&cons[l]) < c + 1 - RD) __builtin_amdgcn_s_sleep(1);
    }

    if (l == 0) {
      float* hdst = &hring[c & (RD - 1)][0][0];
      // prefetch next chunk's x (a whole chunk of latency to hide)
      float xnl = 0.0f;
      if (lane < KK && c + 1 < NC) xnl = xrow[(c + 1) * KK + lane];
      for (int t = 0; t < KK; ++t) {
        const float xv = bcast_dyn(xstage, t);
        const float xr = fmaf(w0own, xv, b0own);
        const float xn = fmaf(w0n, xv, b0n);
        const float gh = matvec();
        const float sv = xr + gh;                 // scaled full preact (r/z rows)
        const float sg = __builtin_amdgcn_rcpf(1.0f + __builtin_amdgcn_exp2f(sv));
        const float zf = shfl_idx(sg, idx20);     // cooked z for unit lane
        const float ghn = shfl_idx(gh, idx40);    // n-gate h-proj (+b_hh_n)
        const float n = ftanh_s(fmaf(sg, ghn, xn));
        hreg = fmaf(zf, hreg - n, n);             // (1-z)*n + z*h
        if (lane < HH) hdst[t * HH + lane] = hreg;   // publish raw h(t)
        refresh_hs();
      }
      xstage = xnl;
    } else if (l == 1) {
      const float* hb = &hring[c & (RD - 1)][0][0];
      float* dst = &xring[1][c & (RD - 1)][0][0];
      for (int t = 0; t < KK; ++t) {
        // wave-uniform broadcast read of h_0(t) (conflict-free)
        const f4* hv = (const f4*)(hb + t * HH);
        const f4 q0 = hv[0], q1 = hv[1], q2 = hv[2], q3 = hv[3], q4 = hv[4];
        f2 h0, h1, h2, h3, h4, h5, h6, h7, h8, h9;
        h0.x = q0.x; h0.y = q0.y;  h1.x = q0.z; h1.y = q0.w;
        h2.x = q1.x; h2.y = q1.y;  h3.x = q1.z; h3.y = q1.w;
        h4.x = q2.x; h4.y = q2.y;  h5.x = q2.z; h5.y = q2.w;
        h6.x = q3.x; h6.y = q3.y;  h7.x = q3.z; h7.y = q3.w;
        h8.x = q4.x; h8.y = q4.y;  h9.x = q4.z; h9.y = q4.w;
        // own-row x-projection, EXACT proj() pairing (bit-identical)
        f2 c0; c0.x = bself; c0.y = 0.0f;
        f2 c1; c1.x = 0.0f;  c1.y = 0.0f;
        c0 = __builtin_elementwise_fma(wself2[0], h0, c0);
        c1 = __builtin_elementwise_fma(wself2[1], h1, c1);
        c0 = __builtin_elementwise_fma(wself2[2], h2, c0);
        c1 = __builtin_elementwise_fma(wself2[3], h3, c1);
        c0 = __builtin_elementwise_fma(wself2[4], h4, c0);
        c1 = __builtin_elementwise_fma(wself2[5], h5, c1);
        c0 = __builtin_elementwise_fma(wself2[6], h6, c0);
        c1 = __builtin_elementwise_fma(wself2[7], h7, c1);
        c0 = __builtin_elementwise_fma(wself2[8], h8, c0);
        c1 = __builtin_elementwise_fma(wself2[9], h9, c1);
        f2 sxy = c0 + c1;
        const float xr = sxy.x + sxy.y;           // == producer's proj value

        const float gh = matvec();
        const float sv = xr + gh;
        const float sg = __builtin_amdgcn_rcpf(1.0f + __builtin_amdgcn_exp2f(sv));
        const float zf = shfl_idx(sg, idx20);
        const float ghn = shfl_idx(gh, idx40);
        const float xnn = shfl_idx(xr, idx40);    // n-row x-proj from lane gn
        if (t > 0) dst[(t - 1) * 64 + lane] = proj();   // shadow: row t-1
        const float n = ftanh_s(fmaf(sg, ghn, xnn));
        hreg = fmaf(zf, hreg - n, n);
        refresh_hs();
      }
      dst[(KK - 1) * 64 + lane] = proj();         // flush last row before flag
    } else if (l < NL - 1) {
      const float* src = &xring[l - 1][c & (RD - 1)][0][0];
      float* dst = &xring[l][c & (RD - 1)][0][0];
      float xr_c = src[g];
      float xn_c = src[gn];
      for (int t = 0; t < KK; ++t) {
        const float* nsrc = src + (t + 1) * 64;   // row KK exists (junk, dead)
        const float xr_n = nsrc[g];
        const float xn_n = nsrc[gn];
        const float gh = matvec();
        const float sv = xr_c + gh;
        const float sg = __builtin_amdgcn_rcpf(1.0f + __builtin_amdgcn_exp2f(sv));
        const float zf = shfl_idx(sg, idx20);
        const float ghn = shfl_idx(gh, idx40);
        if (t > 0) dst[(t - 1) * 64 + lane] = proj();
        const float n = ftanh_s(fmaf(sg, ghn, xn_c));
        hreg = fmaf(zf, hreg - n, n);
        refresh_hs();
        xr_c = xr_n; xn_c = xn_n;
      }
      dst[(KK - 1) * 64 + lane] = proj();
    } else {
      const float* src = &xring[NL - 2][c & (RD - 1)][0][0];
      float* hp = hout + (size_t)c * KK * HH;
      float xr_c = src[g];
      float xn_c = src[gn];
      for (int t = 0; t < KK; ++t) {
        const float* nsrc = src + (t + 1) * 64;
        const float xr_n = nsrc[g];
        const float xn_n = nsrc[gn];
        const float gh = matvec();
        const float sv = xr_c + gh;
        const float sg = __builtin_amdgcn_rcpf(1.0f + __builtin_amdgcn_exp2f(sv));
        const float zf = shfl_idx(sg, idx20);
        const float ghn = shfl_idx(gh, idx40);
        if (t > 0 && lane < HH) hp[(t - 1) * HH + lane] = hreg;  // h(t-1)
        const float n = ftanh_s(fmaf(sg, ghn, xn_c));
        hreg = fmaf(zf, hreg - n, n);
        refresh_hs();                       // keeps hs fresh for next iter
        xr_c = xr_n; xn_c = xn_n;
      }
      if (lane < HH) hp[(KK - 1) * HH + lane] = hreg;
    }

    // --- publish: producer flags chunk done; consumer frees ring slot ---
    if (l < NL - 1) {
      __threadfence_block();               // drain LDS writes before flag
      if (lane == 0) *(volatile int*)&prog[l] = c + 1;
    }
    if (l > 0) {
      if (lane == 0) *(volatile int*)&cons[l - 1] = c + 1;
    }
  }

  // ---- epilogue: h_n + y_hat partial (per wave, then one final barrier) ----
  if (lane < HH)
    p.out[(size_t)BB * TT * HH + (size_t)b * NL * HH + l * HH + lane] = hreg;
  float pp = (lane < HH) ? hreg * p.wout[l * HH + lane] : 0.0f;
  #pragma unroll
  for (int off = 32; off > 0; off >>= 1) pp += __shfl_down(pp, off);
  if (lane == 0) yp[l] = pp;

  __syncthreads();
  if (tid == 0) {
    float y = p.bout[0];
    #pragma unroll
    for (int ll = 0; ll < NL; ++ll) y += yp[ll];
    p.out[(size_t)BB * TT * HH + (size_t)BB * NL * HH + b] = y;
  }
}

extern "C" void kernel_launch(void* const* d_in, const int* in_sizes, int n_in,
                              void* d_out, int out_size, void* d_ws, size_t ws_size,
                              hipStream_t stream) {
  Params p;
  p.x = (const float*)d_in[0];
  for (int l = 0; l < NL; ++l) {
    p.wih[l] = (const float*)d_in[1 + 4 * l];
    p.whh[l] = (const float*)d_in[2 + 4 * l];
    p.bih[l] = (const float*)d_in[3 + 4 * l];
    p.bhh[l] = (const float*)d_in[4 + 4 * l];
  }
  p.wout = (const float*)d_in[1 + 4 * NL];
  p.bout = (const float*)d_in[2 + 4 * NL];
  p.out = (float*)d_out;

  gru5_kernel<<<BB, NL * 64, 0, stream>>>(p);
}

// Round 9
// 880.021 us; speedup vs baseline: 1.6707x; 1.3845x over previous
//
#include <hip/hip_runtime.h>

// 5-layer GRU, H=20, B=256, T=4096, fp32. PyTorch GRU math.
// One block per batch element; 5 waves = one per layer. Lane g owns gate g
// (20-FMA hh matvec); producer wave computes the next layer's input
// projection from the h broadcast. Pre-scaled weights (-log2e on r/z rows,
// -2log2e on n rows) so sigmoid/tanh need no leading multiply. Pairwise
// flag sync on depth-4 ring (no per-chunk __syncthreads).
//
// R14: DS-BROADCAST refresh_hs — replace the 20 v_readlane h-broadcast
// (20 issue slots/step/wave) with 1 ds_write_b32 (lanes 0-19, consecutive
// addrs, conflict-free) + 5 wave-uniform ds_read_b128 (same-address
// broadcast). 6 DS ops replace 20 VALU ops on every wave.
// R15 FIX: R14 omitted a COMPILER fence between the hbuf write and the b128
// reads; the scheduler hoisted the reads above the write (different lvalue
// types, no ordering obligation) -> hs2 stale by one step, absmax 0.122.
// asm volatile("" ::: "memory") is compile-time-only (zero instructions);
// per-wave DS ops execute in order in hardware and the compiler's lgkmcnt
// waits cover the rest -> bits identical to the readlane transport.

#define HH 20
#define GG 60
#define NL 5
#define BB 256
#define TT 4096
#define KK 16
#define NC (TT / KK)
#define RD 4            // ring depth (chunks of drift allowed)

typedef float f2 __attribute__((ext_vector_type(2)));
typedef float f4 __attribute__((ext_vector_type(4)));

struct Params {
  const float* x;
  const float* wih[NL];
  const float* whh[NL];
  const float* bih[NL];
  const float* bhh[NL];
  const float* wout;
  const float* bout;
  float* out;
};

__device__ __forceinline__ float bcast_dyn(float v, int j) {    // j: sgpr
  return __int_as_float(__builtin_amdgcn_readlane(__float_as_int(v), j));
}
__device__ __forceinline__ float shfl_idx(float v, int byteidx) {
  return __int_as_float(__builtin_amdgcn_ds_bpermute(byteidx, __float_as_int(v)));
}
// input pre-scaled by -2log2e: tanh(y) = 2*rcp(1 + exp2(y_scaled)) - 1
__device__ __forceinline__ float ftanh_s(float ys) {
  return fmaf(2.0f, __builtin_amdgcn_rcpf(1.0f + __builtin_amdgcn_exp2f(ys)), -1.0f);
}
__device__ __forceinline__ int ldv(const int* p) {
  return *(const volatile int*)p;
}

__global__ __launch_bounds__(NL * 64, 1) void gru5_kernel(Params p) {
  // ring: producer layer l (0..3) writes xring[l][c%RD]; consumer l+1 reads.
  // KK+1 rows so the consumer's t+1 prefetch is unguarded (row KK = junk).
  __shared__ float xring[NL - 1][RD][KK + 1][64];
  // per-wave h broadcast buffer (write 20 lanes, read back wave-uniform)
  __shared__ __align__(16) float hbuf[NL][32];
  __shared__ float yp[NL];
  __shared__ int prog[NL - 1];   // chunks produced by layer l
  __shared__ int cons[NL - 1];   // chunks consumed by layer l+1

  const int tid = threadIdx.x;
  const int l = tid >> 6;          // wave index == layer
  const int lane = tid & 63;
  const int b = blockIdx.x;
  const int g = lane < GG ? lane : GG - 1;            // gate owned by lane
  const int gn = lane < HH ? lane + 2 * HH : GG - 1;  // n-gate column for unit lane

  if (tid < NL - 1) { prog[tid] = 0; cons[tid] = 0; }

  const float S1 = -1.44269504088896f;   // -log2(e)      (r/z rows)
  const float S2 = -2.88539008177793f;   // -2*log2(e)    (n rows)
  const float scg = (g < 2 * HH) ? S1 : S2;

  // ---- weights into registers (packed pairs), pre-scaled ----
  f2 whh2[HH / 2];
  {
    const float* W = p.whh[l];
    #pragma unroll
    for (int j = 0; j < HH / 2; ++j) {
      whh2[j].x = W[g * HH + 2 * j]     * scg;
      whh2[j].y = W[g * HH + 2 * j + 1] * scg;
    }
  }
  const float binit = (g >= 2 * HH) ? p.bhh[l][g] * S2 : 0.0f;

  f2 wnx2[HH / 2];
  float bnx = 0.0f;
  if (l < NL - 1) {
    const float* W = p.wih[l + 1];
    #pragma unroll
    for (int j = 0; j < HH / 2; ++j) {
      wnx2[j].x = W[g * HH + 2 * j]     * scg;
      wnx2[j].y = W[g * HH + 2 * j + 1] * scg;
    }
    bnx = (p.bih[l + 1][g] + (g < 2 * HH ? p.bhh[l + 1][g] : 0.0f)) * scg;
  } else {
    #pragma unroll
    for (int j = 0; j < HH / 2; ++j) { wnx2[j].x = 0.0f; wnx2[j].y = 0.0f; }
  }
  float w0own = 0.f, b0own = 0.f, w0n = 0.f, b0n = 0.f;
  if (l == 0) {
    w0own = p.wih[0][g] * scg;
    b0own = (p.bih[0][g] + (g < 2 * HH ? p.bhh[0][g] : 0.0f)) * scg;
    w0n = p.wih[0][gn] * S2;
    b0n = p.bih[0][gn] * S2;          // b_ih only (b_hh_n stays in binit)
  }

  const int idx20 = ((lane + 20) & 63) << 2;   // bpermute byte indices
  const int idx40 = ((lane + 40) & 63) << 2;

  float hreg = 0.0f;               // lanes 0..19 carry h[unit]
  f2 hs2[HH / 2];                  // all-lane copy of h (refreshed via LDS)
  #pragma unroll
  for (int j = 0; j < HH / 2; ++j) { hs2[j].x = 0.0f; hs2[j].y = 0.0f; }

  const float* xrow = p.x + (size_t)b * TT;
  float* hout = p.out + (size_t)b * TT * HH;

  // hh matvec: scaled (W_hh h)[g] (+ b_hh_n on n rows)
  auto matvec = [&]() -> float {
    f2 a0; a0.x = binit; a0.y = 0.0f;
    f2 a1; a1.x = 0.0f;  a1.y = 0.0f;
    #pragma unroll
    for (int j = 0; j < HH / 2; j += 2) {
      a0 = __builtin_elementwise_fma(whh2[j],     hs2[j],     a0);
      a1 = __builtin_elementwise_fma(whh2[j + 1], hs2[j + 1], a1);
    }
    f2 s = a0 + a1;
    return s.x + s.y;
  };
  // R15: LDS-broadcast of h with a compiler-only fence. 1 conflict-free
  // ds_write + 5 uniform ds_read_b128 (broadcast) replaces 20 v_readlane.
  // HW executes a wave's DS ops in order; the fence stops the COMPILER from
  // hoisting the reads above the write. Bits identical to readlane.
  auto refresh_hs = [&]() {
    if (lane < HH) hbuf[l][lane] = hreg;
    asm volatile("" ::: "memory");           // compile-time ordering only
    const f4* hv = (const f4*)&hbuf[l][0];
    const f4 q0 = hv[0], q1 = hv[1], q2 = hv[2], q3 = hv[3], q4 = hv[4];
    hs2[0].x = q0.x; hs2[0].y = q0.y;  hs2[1].x = q0.z; hs2[1].y = q0.w;
    hs2[2].x = q1.x; hs2[2].y = q1.y;  hs2[3].x = q1.z; hs2[3].y = q1.w;
    hs2[4].x = q2.x; hs2[4].y = q2.y;  hs2[5].x = q2.z; hs2[5].y = q2.w;
    hs2[6].x = q3.x; hs2[6].y = q3.y;  hs2[7].x = q3.z; hs2[7].y = q3.w;
    hs2[8].x = q4.x; hs2[8].y = q4.y;  hs2[9].x = q4.z; hs2[9].y = q4.w;
  };
  auto proj = [&]() -> float {     // next layer's xg value for this lane
    f2 c0; c0.x = bnx;  c0.y = 0.0f;
    f2 c1; c1.x = 0.0f; c1.y = 0.0f;
    #pragma unroll
    for (int j = 0; j < HH / 2; j += 2) {
      c0 = __builtin_elementwise_fma(wnx2[j],     hs2[j],     c0);
      c1 = __builtin_elementwise_fma(wnx2[j + 1], hs2[j + 1], c1);
    }
    f2 s = c0 + c1;
    return s.x + s.y;
  };

  __syncthreads();                 // flags initialized

  // prime layer-0 x stage for chunk 0 (lanes 0..KK-1 hold the chunk's x)
  float xstage = 0.0f;
  if (l == 0 && lane < KK) xstage = xrow[lane];

  for (int c = 0; c < NC; ++c) {
    // --- sync: wait for input chunk; backpressure on ring slot reuse ---
    if (l > 0) {
      while (ldv(&prog[l - 1]) < c + 1) __builtin_amdgcn_s_sleep(1);
    }
    if (l < NL - 1) {
      while (ldv(&cons[l]) < c + 1 - RD) __builtin_amdgcn_s_sleep(1);
    }

    if (l == 0) {
      float* dst = &xring[0][c & (RD - 1)][0][0];
      // prefetch next chunk's x (a whole chunk of latency to hide)
      float xnl = 0.0f;
      if (lane < KK && c + 1 < NC) xnl = xrow[(c + 1) * KK + lane];
      for (int t = 0; t < KK; ++t) {
        const float xv = bcast_dyn(xstage, t);
        const float xr = fmaf(w0own, xv, b0own);
        const float xn = fmaf(w0n, xv, b0n);
        const float gh = matvec();
        const float sv = xr + gh;                 // scaled full preact (r/z rows)
        const float sg = __builtin_amdgcn_rcpf(1.0f + __builtin_amdgcn_exp2f(sv));
        const float zf = shfl_idx(sg, idx20);     // cooked z for unit lane
        const float ghn = shfl_idx(gh, idx40);    // n-gate h-proj (+b_hh_n)
        if (t > 0) dst[(t - 1) * 64 + lane] = proj();   // shadow: row t-1 (h(t-1))
        const float n = ftanh_s(fmaf(sg, ghn, xn));
        hreg = fmaf(zf, hreg - n, n);             // (1-z)*n + z*h
        refresh_hs();
      }
      dst[(KK - 1) * 64 + lane] = proj();         // flush last row before flag
      xstage = xnl;
    } else if (l < NL - 1) {
      const float* src = &xring[l - 1][c & (RD - 1)][0][0];
      float* dst = &xring[l][c & (RD - 1)][0][0];
      float xr_c = src[g];
      float xn_c = src[gn];
      for (int t = 0; t < KK; ++t) {
        const float* nsrc = src + (t + 1) * 64;   // row KK exists (junk, dead)
        const float xr_n = nsrc[g];
        const float xn_n = nsrc[gn];
        const float gh = matvec();
        const float sv = xr_c + gh;
        const float sg = __builtin_amdgcn_rcpf(1.0f + __builtin_amdgcn_exp2f(sv));
        const float zf = shfl_idx(sg, idx20);
        const float ghn = shfl_idx(gh, idx40);
        if (t > 0) dst[(t - 1) * 64 + lane] = proj();
        const float n = ftanh_s(fmaf(sg, ghn, xn_c));
        hreg = fmaf(zf, hreg - n, n);
        refresh_hs();
        xr_c = xr_n; xn_c = xn_n;
      }
      dst[(KK - 1) * 64 + lane] = proj();
    } else {
      const float* src = &xring[NL - 2][c & (RD - 1)][0][0];
      float* hp = hout + (size_t)c * KK * HH;
      float xr_c = src[g];
      float xn_c = src[gn];
      for (int t = 0; t < KK; ++t) {
        const float* nsrc = src + (t + 1) * 64;
        const float xr_n = nsrc[g];
        const float xn_n = nsrc[gn];
        const float gh = matvec();
        const float sv = xr_c + gh;
        const float sg = __builtin_amdgcn_rcpf(1.0f + __builtin_amdgcn_exp2f(sv));
        const float zf = shfl_idx(sg, idx20);
        const float ghn = shfl_idx(gh, idx40);
        if (t > 0 && lane < HH) hp[(t - 1) * HH + lane] = hreg;  // h(t-1), fire-and-forget
        const float n = ftanh_s(fmaf(sg, ghn, xn_c));
        hreg = fmaf(zf, hreg - n, n);
        refresh_hs();                       // keeps hs fresh for next iter
        xr_c = xr_n; xn_c = xn_n;
      }
      if (lane < HH) hp[(KK - 1) * HH + lane] = hreg;
    }

    // --- publish: producer flags chunk done; consumer frees ring slot ---
    if (l < NL - 1) {
      __threadfence_block();               // drain LDS writes before flag
      if (lane == 0) *(volatile int*)&prog[l] = c + 1;
    }
    if (l > 0) {
      if (lane == 0) *(volatile int*)&cons[l - 1] = c + 1;
    }
  }

  // ---- epilogue: h_n + y_hat partial (per wave, then one final barrier) ----
  if (lane < HH)
    p.out[(size_t)BB * TT * HH + (size_t)b * NL * HH + l * HH + lane] = hreg;
  float pp = (lane < HH) ? hreg * p.wout[l * HH + lane] : 0.0f;
  #pragma unroll
  for (int off = 32; off > 0; off >>= 1) pp += __shfl_down(pp, off);
  if (lane == 0) yp[l] = pp;

  __syncthreads();
  if (tid == 0) {
    float y = p.bout[0];
    #pragma unroll
    for (int ll = 0; ll < NL; ++ll) y += yp[ll];
    p.out[(size_t)BB * TT * HH + (size_t)BB * NL * HH + b] = y;
  }
}

extern "C" void kernel_launch(void* const* d_in, const int* in_sizes, int n_in,
                              void* d_out, int out_size, void* d_ws, size_t ws_size,
                              hipStream_t stream) {
  Params p;
  p.x = (const float*)d_in[0];
  for (int l = 0; l < NL; ++l) {
    p.wih[l] = (const float*)d_in[1 + 4 * l];
    p.whh[l] = (const float*)d_in[2 + 4 * l];
    p.bih[l] = (const float*)d_in[3 + 4 * l];
    p.bhh[l] = (const float*)d_in[4 + 4 * l];
  }
  p.wout = (const float*)d_in[1 + 4 * NL];
  p.bout = (const float*)d_in[2 + 4 * NL];
  p.out = (float*)d_out;

  gru5_kernel<<<BB, NL * 64, 0, stream>>>(p);
}